// Round 6
// baseline (376.781 us; speedup 1.0000x reference)
//
#include <hip/hip_runtime.h>
#include <hip/hip_bf16.h>

// NCC loss: five 9x9x9 box sums over (2,1,160,160,160) fp32, fully fused.
// Round-6 structure: ONE barrier per slice + cross-slice prefetch.
//  - Phase B threads (t<96: row br in [0,24), quad bq in [0,4)) load their 12
//    input floats (3+3 float4) DIRECTLY from global into registers -- no raw
//    halo staging in LDS, no Phase A, no first barrier. Neighbor overlap is
//    served by L1/L2.
//  - Interval: issue loads for slice s+1 -> Phase C(s) from row-sum LDS
//    (latency cover) -> ring/cc -> Phase B(s+1) regs->LDS -> barrier.
//  - Row-sum LDS double-buffered (16.6 KB total).
//  - OOB in any of d/h/w folded into the load predicate (zero-fill == the
//    reference's zero padding), so all steps are uniform.
// D-window ring in registers, slot compile-time via inner unroll-9.
// launch_bounds(256,4): 128-VGPR budget (5 would force <=64 and spill; round-4 lesson).

#define NB   2
#define NDIM 160
#define TILE 16
#define RE   24                  // TILE + 8 halo rows
#define DCHUNK 20
#define NCH  (NDIM / DCHUNK)     // 8
#define PLANE (NDIM * NDIM)
#define NSLICE (DCHUNK + 8)      // 28

#define LOAD_SLICE(dz_)                                                        \
    if (t < 96) {                                                              \
        const bool dok = (unsigned)(dz_) < (unsigned)NDIM;                     \
        const float* pIrow = gI + ((long long)(dz_) * PLANE + rowoff);         \
        const float* pJrow = gJ + ((long long)(dz_) * PLANE + rowoff);         \
        aI0 = (dok && c0ok) ? *(const float4*)(pIrow)     : f4z;               \
        aI1 = (dok && c1ok) ? *(const float4*)(pIrow + 4) : f4z;               \
        aI2 = (dok && c2ok) ? *(const float4*)(pIrow + 8) : f4z;               \
        aJ0 = (dok && c0ok) ? *(const float4*)(pJrow)     : f4z;               \
        aJ1 = (dok && c1ok) ? *(const float4*)(pJrow + 4) : f4z;               \
        aJ2 = (dok && c2ok) ? *(const float4*)(pJrow + 8) : f4z;               \
    }

#define BCOMP(pbx_)                                                            \
    if (t < 96) {                                                              \
        const float i0=aI0.x, i1=aI0.y, i2=aI0.z, i3=aI0.w;                    \
        const float i4=aI1.x, i5=aI1.y, i6=aI1.z, i7=aI1.w;                    \
        const float i8=aI2.x, i9=aI2.y, iA=aI2.z, iB=aI2.w;                    \
        const float j0=aJ0.x, j1=aJ0.y, j2=aJ0.z, j3=aJ0.w;                    \
        const float j4=aJ1.x, j5=aJ1.y, j6=aJ1.z, j7=aJ1.w;                    \
        const float j8=aJ2.x, j9=aJ2.y, jA=aJ2.z, jB=aJ2.w;                    \
        const int wo = bq << 2;                                                \
        float sA = i0+i1+i2+i3+i4+i5+i6+i7+i8;                                 \
        float sB = j0+j1+j2+j3+j4+j5+j6+j7+j8;                                 \
        float sC = i0*i0+i1*i1+i2*i2+i3*i3+i4*i4+i5*i5+i6*i6+i7*i7+i8*i8;      \
        float sD = j0*j0+j1*j1+j2*j2+j3*j3+j4*j4+j5*j5+j6*j6+j7*j7+j8*j8;      \
        float sE = i0*j0+i1*j1+i2*j2+i3*j3+i4*j4+i5*j5+i6*j6+i7*j7+i8*j8;      \
        rsv[pbx_][br][wo] = make_float4(sA, sB, sC, sD); rss[pbx_][br][wo] = sE; \
        sA += i9-i0; sB += j9-j0; sC += i9*i9-i0*i0; sD += j9*j9-j0*j0; sE += i9*j9-i0*j0; \
        rsv[pbx_][br][wo+1] = make_float4(sA, sB, sC, sD); rss[pbx_][br][wo+1] = sE; \
        sA += iA-i1; sB += jA-j1; sC += iA*iA-i1*i1; sD += jA*jA-j1*j1; sE += iA*jA-i1*j1; \
        rsv[pbx_][br][wo+2] = make_float4(sA, sB, sC, sD); rss[pbx_][br][wo+2] = sE; \
        sA += iB-i2; sB += jB-j2; sC += iB*iB-i2*i2; sD += jB*jB-j2*j2; sE += iB*jB-i2*j2; \
        rsv[pbx_][br][wo+3] = make_float4(sA, sB, sC, sD); rss[pbx_][br][wo+3] = sE; \
    }

__global__ __launch_bounds__(256, 4)
void ncc_main(const float* __restrict__ I, const float* __restrict__ J,
              double* __restrict__ out_acc) {
    const int t  = threadIdx.x;
    const int tx = t & 15;
    const int ty = t >> 4;
    const int w0 = blockIdx.x * TILE;
    const int h0 = blockIdx.y * TILE;
    const int b  = blockIdx.z / NCH;
    const int d0 = (blockIdx.z % NCH) * DCHUNK;

    const float* gI = I + (size_t)b * NDIM * PLANE;
    const float* gJ = J + (size_t)b * NDIM * PLANE;

    __shared__ float4 rsv[2][RE][17];   // row sums {I, J, I2, J2}
    __shared__ float  rss[2][RE][17];   // row sums IJ
    __shared__ double wsum[4];

    // B-thread geometry (t < 96): outputs wo = 4*bq .. 4*bq+3 on row br.
    const int br = t >> 2;
    const int bq = t & 3;
    const int bh = h0 - 4 + br;
    const int bw = w0 - 4 + (bq << 2);
    const bool rowok = (unsigned)bh < (unsigned)NDIM;
    const bool c0ok = rowok && (unsigned)(bw)     < (unsigned)NDIM;
    const bool c1ok = rowok && (unsigned)(bw + 4) < (unsigned)NDIM;
    const bool c2ok = rowok && (unsigned)(bw + 8) < (unsigned)NDIM;
    const long long rowoff = (long long)bh * NDIM + bw;
    const float4 f4z = make_float4(0.f, 0.f, 0.f, 0.f);

    float4 aI0, aI1, aI2, aJ0, aJ1, aJ2;

    // D-window ring in registers; slot j is always a compile-time constant.
    float ring[9][5];
#pragma unroll
    for (int k = 0; k < 9; ++k)
#pragma unroll
        for (int c = 0; c < 5; ++c) ring[k][c] = 0.0f;

    float acc[5] = {0.f, 0.f, 0.f, 0.f, 0.f};
    double csum = 0.0;
    const float inv_win = 1.0f / 729.0f;

    // Prologue: stage slice step=0 (dz = d0-4; OOB => zeros) into buffer 0.
    LOAD_SLICE(d0 - 4)
    BCOMP(0)
    __syncthreads();

    int pb = 0;
    for (int o = 0; o < 4; ++o) {
#pragma unroll
        for (int j = 0; j < 9; ++j) {
            const int step = o * 9 + j;
            if (step < NSLICE) {                       // block-uniform
                // Prefetch next slice's inputs (consumed by BCOMP below).
                if (step + 1 < NSLICE) {
                    LOAD_SLICE(d0 - 3 + step)
                }
                // Phase C: 9-tap column sums of slice (d0-4+step) at (ty,tx).
                float s0 = 0.f, s1 = 0.f, s2 = 0.f, s3 = 0.f, s4 = 0.f;
#pragma unroll
                for (int k = 0; k < 9; ++k) {
                    float4 v = rsv[pb][ty + k][tx];
                    s0 += v.x; s1 += v.y; s2 += v.z; s3 += v.w;
                    s4 += rss[pb][ty + k][tx];
                }
                // Slide the D-window (constant slot j -> registers).
                acc[0] += s0 - ring[j][0]; ring[j][0] = s0;
                acc[1] += s1 - ring[j][1]; ring[j][1] = s1;
                acc[2] += s2 - ring[j][2]; ring[j][2] = s2;
                acc[3] += s3 - ring[j][3]; ring[j][3] = s3;
                acc[4] += s4 - ring[j][4]; ring[j][4] = s4;
                if (step >= 8) {
                    float Is = acc[0], Js = acc[1];
                    float I2 = acc[2], J2 = acc[3], IJ = acc[4];
                    float cross = IJ - Is * Js * inv_win;
                    float Ivar  = I2 - Is * Is * inv_win;
                    float Jvar  = J2 - Js * Js * inv_win;
                    float cc = cross * cross / (Ivar * Jvar + 1e-5f);
                    csum += (double)cc;
                }
                // Phase B: row sums of the prefetched slice into other buffer.
                if (step + 1 < NSLICE) {
                    BCOMP(pb ^ 1)
                }
                __syncthreads();
                pb ^= 1;
            }
        }
    }

    // Block reduction: wave shuffle, then cross-wave via LDS.
#pragma unroll
    for (int off = 32; off > 0; off >>= 1)
        csum += __shfl_down(csum, off, 64);
    if ((t & 63) == 0) wsum[t >> 6] = csum;
    __syncthreads();
    if (t == 0) {
        double total = wsum[0] + wsum[1] + wsum[2] + wsum[3];
        atomicAdd(out_acc, total);
    }
}

__global__ void ncc_finalize(const double* __restrict__ acc,
                             float* __restrict__ out) {
    out[0] = (float)(-acc[0] / 8192000.0);
}

extern "C" void kernel_launch(void* const* d_in, const int* in_sizes, int n_in,
                              void* d_out, int out_size, void* d_ws, size_t ws_size,
                              hipStream_t stream) {
    const float* I = (const float*)d_in[0];   // y_true
    const float* J = (const float*)d_in[1];   // y_pred
    double* acc = (double*)d_ws;

    hipMemsetAsync(acc, 0, sizeof(double), stream);

    dim3 grid(NDIM / TILE, NDIM / TILE, NB * NCH);  // 10 x 10 x 16
    ncc_main<<<grid, 256, 0, stream>>>(I, J, acc);
    ncc_finalize<<<1, 1, 0, stream>>>(acc, (float*)d_out);
}

// Round 7
// 365.889 us; speedup vs baseline: 1.0298x; 1.0298x over previous
//
#include <hip/hip_runtime.h>
#include <hip/hip_bf16.h>

// NCC loss: five 9x9x9 box sums over (2,1,160,160,160) fp32, fully fused.
// Structure (round 6): ONE barrier per slice + cross-slice register prefetch.
//  - Phase B threads (t<96: row br in [0,24), quad bq in [0,4)) load their 12
//    input floats (3+3 float4) directly from global into registers.
//  - Interval: issue loads for slice s+1 -> Phase C(s) from row-sum LDS
//    (latency cover) -> ring/cc -> Phase B(s+1) regs->LDS -> barrier.
//  - Row-sum LDS double-buffered (16.6 KB).
//
// REGISTER-BUDGET NOTE (round 4/6 lessons): __launch_bounds__(256,N) only
// sets the MIN waves/EU; the allocator still targets 8 waves/EU (64 VGPRs)
// and spills to get there (round 6: 155 MB scratch WRITE_SIZE, VALUBusy 12%).
// amdgpu_waves_per_eu(4,4) pins min=max=4 -> exact 128-VGPR budget, no spill.

#define NB   2
#define NDIM 160
#define TILE 16
#define RE   24                  // TILE + 8 halo rows
#define DCHUNK 20
#define NCH  (NDIM / DCHUNK)     // 8
#define PLANE (NDIM * NDIM)
#define NSLICE (DCHUNK + 8)      // 28

#define LOAD_SLICE(dz_)                                                        \
    if (t < 96) {                                                              \
        const bool dok = (unsigned)(dz_) < (unsigned)NDIM;                     \
        const float* pIrow = gI + loff;                                        \
        const float* pJrow = gJ + loff;                                        \
        aI0 = (dok && c0ok) ? *(const float4*)(pIrow)     : f4z;               \
        aI1 = (dok && c1ok) ? *(const float4*)(pIrow + 4) : f4z;               \
        aI2 = (dok && c2ok) ? *(const float4*)(pIrow + 8) : f4z;               \
        aJ0 = (dok && c0ok) ? *(const float4*)(pJrow)     : f4z;               \
        aJ1 = (dok && c1ok) ? *(const float4*)(pJrow + 4) : f4z;               \
        aJ2 = (dok && c2ok) ? *(const float4*)(pJrow + 8) : f4z;               \
    }

#define BCOMP(pbx_)                                                            \
    if (t < 96) {                                                              \
        const float i0=aI0.x, i1=aI0.y, i2=aI0.z, i3=aI0.w;                    \
        const float i4=aI1.x, i5=aI1.y, i6=aI1.z, i7=aI1.w;                    \
        const float i8=aI2.x, i9=aI2.y, iA=aI2.z, iB=aI2.w;                    \
        const float j0=aJ0.x, j1=aJ0.y, j2=aJ0.z, j3=aJ0.w;                    \
        const float j4=aJ1.x, j5=aJ1.y, j6=aJ1.z, j7=aJ1.w;                    \
        const float j8=aJ2.x, j9=aJ2.y, jA=aJ2.z, jB=aJ2.w;                    \
        const int wo = bq << 2;                                                \
        float sA = i0+i1+i2+i3+i4+i5+i6+i7+i8;                                 \
        float sB = j0+j1+j2+j3+j4+j5+j6+j7+j8;                                 \
        float sC = i0*i0+i1*i1+i2*i2+i3*i3+i4*i4+i5*i5+i6*i6+i7*i7+i8*i8;      \
        float sD = j0*j0+j1*j1+j2*j2+j3*j3+j4*j4+j5*j5+j6*j6+j7*j7+j8*j8;      \
        float sE = i0*j0+i1*j1+i2*j2+i3*j3+i4*j4+i5*j5+i6*j6+i7*j7+i8*j8;      \
        rsv[pbx_][br][wo] = make_float4(sA, sB, sC, sD); rss[pbx_][br][wo] = sE; \
        sA += i9-i0; sB += j9-j0; sC += i9*i9-i0*i0; sD += j9*j9-j0*j0; sE += i9*j9-i0*j0; \
        rsv[pbx_][br][wo+1] = make_float4(sA, sB, sC, sD); rss[pbx_][br][wo+1] = sE; \
        sA += iA-i1; sB += jA-j1; sC += iA*iA-i1*i1; sD += jA*jA-j1*j1; sE += iA*jA-i1*j1; \
        rsv[pbx_][br][wo+2] = make_float4(sA, sB, sC, sD); rss[pbx_][br][wo+2] = sE; \
        sA += iB-i2; sB += jB-j2; sC += iB*iB-i2*i2; sD += jB*jB-j2*j2; sE += iB*jB-i2*j2; \
        rsv[pbx_][br][wo+3] = make_float4(sA, sB, sC, sD); rss[pbx_][br][wo+3] = sE; \
    }

__global__ __launch_bounds__(256)
__attribute__((amdgpu_waves_per_eu(4, 4)))
void ncc_main(const float* __restrict__ I, const float* __restrict__ J,
              double* __restrict__ out_acc) {
    const int t  = threadIdx.x;
    const int tx = t & 15;
    const int ty = t >> 4;
    const int w0 = blockIdx.x * TILE;
    const int h0 = blockIdx.y * TILE;
    const int b  = blockIdx.z / NCH;
    const int d0 = (blockIdx.z % NCH) * DCHUNK;

    const float* gI = I + (size_t)b * NDIM * PLANE;
    const float* gJ = J + (size_t)b * NDIM * PLANE;

    __shared__ float4 rsv[2][RE][17];   // row sums {I, J, I2, J2}
    __shared__ float  rss[2][RE][17];   // row sums IJ
    __shared__ double wsum[4];

    // B-thread geometry (t < 96): outputs wo = 4*bq .. 4*bq+3 on row br.
    const int br = t >> 2;
    const int bq = t & 3;
    const int bh = h0 - 4 + br;
    const int bw = w0 - 4 + (bq << 2);
    const bool rowok = (unsigned)bh < (unsigned)NDIM;
    const bool c0ok = rowok && (unsigned)(bw)     < (unsigned)NDIM;
    const bool c1ok = rowok && (unsigned)(bw + 4) < (unsigned)NDIM;
    const bool c2ok = rowok && (unsigned)(bw + 8) < (unsigned)NDIM;
    const float4 f4z = make_float4(0.f, 0.f, 0.f, 0.f);

    // Rolling within-volume offset of this thread's row for the slice being
    // loaded; advanced by PLANE after each load (no per-slice multiply).
    long long loff = (long long)(d0 - 4) * PLANE + (long long)bh * NDIM + bw;

    float4 aI0, aI1, aI2, aJ0, aJ1, aJ2;

    // D-window ring in registers; slot j is always a compile-time constant.
    float ring[9][5];
#pragma unroll
    for (int k = 0; k < 9; ++k)
#pragma unroll
        for (int c = 0; c < 5; ++c) ring[k][c] = 0.0f;

    float acc[5] = {0.f, 0.f, 0.f, 0.f, 0.f};
    double csum = 0.0;
    const float inv_win = 1.0f / 729.0f;

    // Prologue: stage slice step=0 (dz = d0-4; OOB => zeros) into buffer 0.
    LOAD_SLICE(d0 - 4)
    loff += PLANE;
    BCOMP(0)
    __syncthreads();

    int pb = 0;
    for (int o = 0; o < 4; ++o) {
#pragma unroll
        for (int j = 0; j < 9; ++j) {
            const int step = o * 9 + j;
            if (step < NSLICE) {                       // block-uniform
                // Prefetch next slice's inputs (consumed by BCOMP below).
                if (step + 1 < NSLICE) {
                    LOAD_SLICE(d0 - 3 + step)
                    loff += PLANE;
                }
                // Phase C: 9-tap column sums of slice (d0-4+step) at (ty,tx).
                float s0 = 0.f, s1 = 0.f, s2 = 0.f, s3 = 0.f, s4 = 0.f;
#pragma unroll
                for (int k = 0; k < 9; ++k) {
                    float4 v = rsv[pb][ty + k][tx];
                    s0 += v.x; s1 += v.y; s2 += v.z; s3 += v.w;
                    s4 += rss[pb][ty + k][tx];
                }
                // Slide the D-window (constant slot j -> registers).
                acc[0] += s0 - ring[j][0]; ring[j][0] = s0;
                acc[1] += s1 - ring[j][1]; ring[j][1] = s1;
                acc[2] += s2 - ring[j][2]; ring[j][2] = s2;
                acc[3] += s3 - ring[j][3]; ring[j][3] = s3;
                acc[4] += s4 - ring[j][4]; ring[j][4] = s4;
                if (step >= 8) {
                    float Is = acc[0], Js = acc[1];
                    float I2 = acc[2], J2 = acc[3], IJ = acc[4];
                    float cross = IJ - Is * Js * inv_win;
                    float Ivar  = I2 - Is * Is * inv_win;
                    float Jvar  = J2 - Js * Js * inv_win;
                    float cc = cross * cross / (Ivar * Jvar + 1e-5f);
                    csum += (double)cc;
                }
                // Phase B: row sums of the prefetched slice into other buffer.
                if (step + 1 < NSLICE) {
                    BCOMP(pb ^ 1)
                }
                __syncthreads();
                pb ^= 1;
            }
        }
    }

    // Block reduction: wave shuffle, then cross-wave via LDS.
#pragma unroll
    for (int off = 32; off > 0; off >>= 1)
        csum += __shfl_down(csum, off, 64);
    if ((t & 63) == 0) wsum[t >> 6] = csum;
    __syncthreads();
    if (t == 0) {
        double total = wsum[0] + wsum[1] + wsum[2] + wsum[3];
        atomicAdd(out_acc, total);
    }
}

__global__ void ncc_finalize(const double* __restrict__ acc,
                             float* __restrict__ out) {
    out[0] = (float)(-acc[0] / 8192000.0);
}

extern "C" void kernel_launch(void* const* d_in, const int* in_sizes, int n_in,
                              void* d_out, int out_size, void* d_ws, size_t ws_size,
                              hipStream_t stream) {
    const float* I = (const float*)d_in[0];   // y_true
    const float* J = (const float*)d_in[1];   // y_pred
    double* acc = (double*)d_ws;

    hipMemsetAsync(acc, 0, sizeof(double), stream);

    dim3 grid(NDIM / TILE, NDIM / TILE, NB * NCH);  // 10 x 10 x 16
    ncc_main<<<grid, 256, 0, stream>>>(I, J, acc);
    ncc_finalize<<<1, 1, 0, stream>>>(acc, (float*)d_out);
}